// Round 1
// baseline (593.551 us; speedup 1.0000x reference)
//
#include <hip/hip_runtime.h>

typedef unsigned short u16;
typedef unsigned int u32;
typedef __attribute__((ext_vector_type(8))) short s16x8;
typedef __attribute__((ext_vector_type(4))) float f32x4;

#define IS_ 1024
#define LTOK 16

__device__ __forceinline__ u16 f2bf(float f) {
  u32 u = __builtin_bit_cast(u32, f);
  u32 r = (u + 0x7FFFu + ((u >> 16) & 1u)) >> 16;
  return (u16)r;
}

__device__ __forceinline__ float dot4(const float4& a, const float4& b) {
  return a.x * b.x + a.y * b.y + a.z * b.z + a.w * b.w;
}

// ---------------- k_pre0: offs prefix-sum + seg fill ----------------
__global__ void k_pre0(const int* __restrict__ l_hs, int* __restrict__ offs,
                       int* __restrict__ seg, int Bn, int Tn, int Mp) {
  __shared__ int so[65];
  const int tid = threadIdx.x;
  if (tid < 64) {
    int v = (tid < Bn) ? l_hs[tid] : 0;
#pragma unroll
    for (int off = 1; off < 64; off <<= 1) {
      int up = __shfl_up(v, off, 64);
      if (tid >= off) v += up;
    }
    so[tid + 1] = v;
    if (tid == 0) so[0] = 0;
  }
  __syncthreads();
  if (tid < 65) offs[tid] = so[tid];
  for (int t = tid; t < Mp; t += 256) {
    int s = 0;
    if (t < Tn) {
      int lo = 0, hi = Bn;
      while (hi - lo > 1) {
        int mid = (lo + hi) >> 1;
        if (so[mid] <= t) lo = mid; else hi = mid;
      }
      s = lo;
    }
    seg[t] = s;
  }
}

// ---------------- k_convW1: enc_w[:, :1024] -> bf16 ----------------
__global__ __launch_bounds__(256) void k_convW1(const float* __restrict__ enc_w,
                                                u16* __restrict__ W1) {
  const int i = blockIdx.x * 1024 + threadIdx.x * 4;  // [0, 1M)
  const int r = i >> 10, k = i & 1023;
  float4 v = *(const float4*)&enc_w[(size_t)r * 2048 + k];
  uint2 pk;
  pk.x = (u32)f2bf(v.x) | ((u32)f2bf(v.y) << 16);
  pk.y = (u32)f2bf(v.z) | ((u32)f2bf(v.w) << 16);
  *(uint2*)&W1[i] = pk;
}

// -------- k_rowdot: out[b,d] = bias[d] + sum_e x[b,e]*W[d*ldW+colOff+e] -----
// used for wenc_u (U_w) and h2 (enc_w right half + enc_b). btile=2.
__global__ __launch_bounds__(256) void k_rowdot(const float* __restrict__ x,
                                                const float* __restrict__ W,
                                                const float* __restrict__ bias,
                                                float* __restrict__ outp,
                                                int ldW, int colOff) {
  __shared__ float cs[2][IS_];
  const int tid = threadIdx.x;
  const int b0 = blockIdx.y * 2;
  const int d = blockIdx.x * 256 + tid;
#pragma unroll
  for (int i = 0; i < 8; ++i) {
    int idx = i * 256 + tid;  // 0..2047
    cs[idx >> 10][idx & 1023] = x[(b0 + (idx >> 10)) * IS_ + (idx & 1023)];
  }
  __syncthreads();
  float a0 = bias[d];
  float a1 = a0;
  const float* wr = W + (size_t)d * ldW + colOff;
#pragma unroll 4
  for (int e = 0; e < IS_; e += 4) {
    float4 w4 = *(const float4*)(wr + e);
    float4 c0 = *(const float4*)&cs[0][e];
    float4 c1 = *(const float4*)&cs[1][e];
    a0 += dot4(w4, c0);
    a1 += dot4(w4, c1);
  }
  outp[b0 * IS_ + d] = a0;
  outp[(b0 + 1) * IS_ + d] = a1;
}

// -------- k_preQ: q2[b,e] = sum_d wenc_u[b,d] * V_w[d,e]  (btile=2) --------
__global__ __launch_bounds__(256) void k_preQ(const float* __restrict__ wencu,
                                              const float* __restrict__ Vw,
                                              float* __restrict__ q2) {
  __shared__ float us[2][IS_];
  const int tid = threadIdx.x;
  const int b0 = blockIdx.y * 2;
  const int e = blockIdx.x * 256 + tid;
#pragma unroll
  for (int i = 0; i < 8; ++i) {
    int idx = i * 256 + tid;
    us[idx >> 10][idx & 1023] = wencu[(b0 + (idx >> 10)) * IS_ + (idx & 1023)];
  }
  __syncthreads();
  float a0 = 0.f, a1 = 0.f;
#pragma unroll 2
  for (int dd = 0; dd < IS_; dd += 4) {
    float4 u0 = *(const float4*)&us[0][dd];
    float4 u1 = *(const float4*)&us[1][dd];
    float v0 = Vw[(size_t)(dd + 0) * IS_ + e];
    float v1 = Vw[(size_t)(dd + 1) * IS_ + e];
    float v2 = Vw[(size_t)(dd + 2) * IS_ + e];
    float v3 = Vw[(size_t)(dd + 3) * IS_ + e];
    a0 += u0.x * v0 + u0.y * v1 + u0.z * v2 + u0.w * v3;
    a1 += u1.x * v0 + u1.y * v1 + u1.z * v2 + u1.w * v3;
  }
  q2[b0 * IS_ + e] = a0;
  q2[(b0 + 1) * IS_ + e] = a1;
}

// ---------------- k_attn: scores + softmax + pooled (bf16) ----------------
__global__ __launch_bounds__(256) void k_attn(const float* __restrict__ wemb,
                                              const float* __restrict__ q2,
                                              const int* __restrict__ seg,
                                              u16* __restrict__ pooled, int Tn) {
  const int t = blockIdx.x;
  const int tid = threadIdx.x;
  const int d4 = tid * 4;
  if (t >= Tn) {
    uint2 z; z.x = 0u; z.y = 0u;
    *(uint2*)&pooled[(size_t)t * IS_ + d4] = z;
    return;
  }
  const int b = seg[t];
  float4 q = *(const float4*)&q2[b * IS_ + d4];
  float4 w[LTOK];
  const float* base = wemb + (size_t)t * (LTOK * IS_) + d4;
#pragma unroll
  for (int l = 0; l < LTOK; ++l) w[l] = *(const float4*)(base + l * IS_);
  float s[LTOK];
#pragma unroll
  for (int l = 0; l < LTOK; ++l) s[l] = dot4(w[l], q);
#pragma unroll
  for (int l = 0; l < LTOK; ++l) {
#pragma unroll
    for (int m = 1; m < 64; m <<= 1) s[l] += __shfl_xor(s[l], m, 64);
  }
  __shared__ float sred[4][LTOK];
  const int wave = tid >> 6, lane = tid & 63;
  if (lane == 0) {
#pragma unroll
    for (int l = 0; l < LTOK; ++l) sred[wave][l] = s[l];
  }
  __syncthreads();
  float sc[LTOK];
#pragma unroll
  for (int l = 0; l < LTOK; ++l)
    sc[l] = sred[0][l] + sred[1][l] + sred[2][l] + sred[3][l];
  float mx = sc[0];
#pragma unroll
  for (int l = 1; l < LTOK; ++l) mx = fmaxf(mx, sc[l]);
  float den = 0.f;
#pragma unroll
  for (int l = 0; l < LTOK; ++l) { sc[l] = __expf(sc[l] - mx); den += sc[l]; }
  const float inv = 1.f / den;
  float px = 0.f, py = 0.f, pz = 0.f, pw = 0.f;
#pragma unroll
  for (int l = 0; l < LTOK; ++l) {
    float a = sc[l] * inv;
    px += a * w[l].x; py += a * w[l].y; pz += a * w[l].z; pw += a * w[l].w;
  }
  uint2 pk;
  pk.x = (u32)f2bf(px) | ((u32)f2bf(py) << 16);
  pk.y = (u32)f2bf(pz) | ((u32)f2bf(pw) << 16);
  *(uint2*)&pooled[(size_t)t * IS_ + d4] = pk;
}

// ---------------- k_gemm: h[M,1024] = pooled[M,1024] @ W1[1024,1024]^T -----
__device__ __forceinline__ void gl2lds16(const void* g, void* l) {
  __builtin_amdgcn_global_load_lds(
      (const __attribute__((address_space(1))) u32*)g,
      (__attribute__((address_space(3))) u32*)l, 16, 0, 0);
}

__global__ __launch_bounds__(256) void k_gemm(const u16* __restrict__ A,
                                              const u16* __restrict__ B,
                                              float* __restrict__ C) {
  __shared__ __align__(16) u16 As[128 * 64];
  __shared__ __align__(16) u16 Bs[128 * 64];
  const int tid = threadIdx.x;
  const int wave = tid >> 6, lane = tid & 63;
  const int m0 = blockIdx.x * 128, n0 = blockIdx.y * 128;
  const int wm = (wave & 1) * 64, wn = (wave >> 1) * 64;
  f32x4 acc[4][4] = {};
  for (int kt = 0; kt < 1024; kt += 64) {
#pragma unroll
    for (int c = 0; c < 4; ++c) {
      int idx = c * 256 + tid;       // 0..1023
      int row = idx >> 3;            // 0..127
      int kk = (idx & 7) * 8;        // 0..56
      gl2lds16(A + (size_t)(m0 + row) * 1024 + kt + kk, &As[idx * 8]);
      gl2lds16(B + (size_t)(n0 + row) * 1024 + kt + kk, &Bs[idx * 8]);
    }
    __syncthreads();
#pragma unroll
    for (int ks = 0; ks < 2; ++ks) {
      const int kb = ks * 32 + (lane >> 4) * 8;
      const int rr = lane & 15;
      s16x8 af[4], bf[4];
#pragma unroll
      for (int i = 0; i < 4; ++i) {
        af[i] = *(const s16x8*)&As[(wm + i * 16 + rr) * 64 + kb];
        bf[i] = *(const s16x8*)&Bs[(wn + i * 16 + rr) * 64 + kb];
      }
#pragma unroll
      for (int i = 0; i < 4; ++i)
#pragma unroll
        for (int j = 0; j < 4; ++j)
          acc[i][j] = __builtin_amdgcn_mfma_f32_16x16x32_bf16(af[i], bf[j], acc[i][j], 0, 0, 0);
    }
    __syncthreads();
  }
  const int col = lane & 15, rq = (lane >> 4) * 4;
#pragma unroll
  for (int i = 0; i < 4; ++i)
#pragma unroll
    for (int j = 0; j < 4; ++j) {
#pragma unroll
      for (int r = 0; r < 4; ++r)
        C[(size_t)(m0 + wm + i * 16 + rq + r) * 1024 + (n0 + wn + j * 16 + col)] = acc[i][j][r];
    }
}

// ---------------- k_ln: +h2[seg], LayerNorm, scatter to padded -------------
__global__ __launch_bounds__(256) void k_ln(const float* __restrict__ h,
                                            const float* __restrict__ h2,
                                            const int* __restrict__ offs,
                                            const int* __restrict__ l_hs,
                                            const float* __restrict__ gamma,
                                            const float* __restrict__ beta,
                                            float* __restrict__ out, int maxL) {
  const int row = blockIdx.x;
  const int b = row / maxL, pos = row % maxL;
  const int tid = threadIdx.x, d4 = tid * 4;
  float4 be = *(const float4*)&beta[d4];
  float* orow = out + (size_t)row * IS_;
  if (pos >= l_hs[b]) {
    *(float4*)(orow + d4) = be;
    return;
  }
  const int t = offs[b] + pos;
  float4 x = *(const float4*)&h[(size_t)t * IS_ + d4];
  float4 y2 = *(const float4*)&h2[b * IS_ + d4];
  x.x += y2.x; x.y += y2.y; x.z += y2.z; x.w += y2.w;
  float s1 = x.x + x.y + x.z + x.w;
  float s2 = x.x * x.x + x.y * x.y + x.z * x.z + x.w * x.w;
#pragma unroll
  for (int m = 1; m < 64; m <<= 1) {
    s1 += __shfl_xor(s1, m, 64);
    s2 += __shfl_xor(s2, m, 64);
  }
  __shared__ float red[4][2];
  const int wave = tid >> 6, lane = tid & 63;
  if (lane == 0) { red[wave][0] = s1; red[wave][1] = s2; }
  __syncthreads();
  float S1 = red[0][0] + red[1][0] + red[2][0] + red[3][0];
  float S2 = red[0][1] + red[1][1] + red[2][1] + red[3][1];
  const float u = S1 * (1.f / 1024.f);
  const float var = S2 * (1.f / 1024.f) - u * u;
  const float rstd = rsqrtf(var + 1e-12f);
  float4 g = *(const float4*)&gamma[d4];
  float4 o;
  o.x = g.x * (x.x - u) * rstd + be.x;
  o.y = g.y * (x.y - u) * rstd + be.y;
  o.z = g.z * (x.z - u) * rstd + be.z;
  o.w = g.w * (x.w - u) * rstd + be.w;
  *(float4*)(orow + d4) = o;
}

extern "C" void kernel_launch(void* const* d_in, const int* in_sizes, int n_in,
                              void* d_out, int out_size, void* d_ws, size_t ws_size,
                              hipStream_t stream) {
  const float* ctx   = (const float*)d_in[0];
  const float* wemb  = (const float*)d_in[1];
  const int*   l_hs  = (const int*)d_in[3];
  const float* U_w   = (const float*)d_in[5];
  const float* U_b   = (const float*)d_in[6];
  const float* V_w   = (const float*)d_in[7];
  // d_in[8] = V_b: constant-per-row score shift -> cancels in softmax
  const float* enc_w = (const float*)d_in[9];
  const float* enc_b = (const float*)d_in[10];
  const float* gamma = (const float*)d_in[11];
  const float* beta  = (const float*)d_in[12];
  float* out = (float*)d_out;

  const int Bn = in_sizes[0] / IS_;               // 64
  const int Tn = in_sizes[1] / (LTOK * IS_);      // 4064
  const int maxL = out_size / (Bn * IS_);         // 95
  const int Mp = (Tn + 127) & ~127;               // 4096

  char* ws = (char*)d_ws;
  int*   offs   = (int*)(ws + 0x0);
  int*   seg    = (int*)(ws + 0x400);
  float* wencu  = (float*)(ws + 0x10000);
  float* q2     = (float*)(ws + 0x50000);
  float* h2     = (float*)(ws + 0x90000);
  u16*   W1     = (u16*)(ws + 0xD0000);
  u16*   pooled = (u16*)(ws + 0x2D0000);
  float* h      = (float*)(ws + 0xAD0000);

  k_pre0<<<1, 256, 0, stream>>>(l_hs, offs, seg, Bn, Tn, Mp);
  k_convW1<<<1024, 256, 0, stream>>>(enc_w, W1);
  k_rowdot<<<dim3(4, Bn / 2), 256, 0, stream>>>(ctx, U_w, U_b, wencu, 1024, 0);
  k_rowdot<<<dim3(4, Bn / 2), 256, 0, stream>>>(ctx, enc_w, enc_b, h2, 2048, 1024);
  k_preQ<<<dim3(4, Bn / 2), 256, 0, stream>>>(wencu, V_w, q2);
  k_attn<<<Mp, 256, 0, stream>>>(wemb, q2, seg, pooled, Tn);
  k_gemm<<<dim3(Mp / 128, 8), 256, 0, stream>>>(pooled, W1, h);
  k_ln<<<Bn * maxL, 256, 0, stream>>>(h, h2, offs, l_hs, gamma, beta, out, maxL);
}

// Round 2
// 498.896 us; speedup vs baseline: 1.1897x; 1.1897x over previous
//
#include <hip/hip_runtime.h>

typedef unsigned short u16;
typedef unsigned int u32;
typedef __attribute__((ext_vector_type(8))) short s16x8;
typedef __attribute__((ext_vector_type(4))) float f32x4;

#define IS_ 1024
#define LTOK 16

__device__ __forceinline__ u16 f2bf(float f) {
  u32 u = __builtin_bit_cast(u32, f);
  u32 r = (u + 0x7FFFu + ((u >> 16) & 1u)) >> 16;
  return (u16)r;
}

__device__ __forceinline__ float dot4(const float4& a, const float4& b) {
  return a.x * b.x + a.y * b.y + a.z * b.z + a.w * b.w;
}

// ---- k_prep: enc_w[:, :1024] -> bf16 (all blocks) + offs/seg (block 0) ----
__global__ __launch_bounds__(256) void k_prep(const float* __restrict__ enc_w,
                                              u16* __restrict__ W1,
                                              const int* __restrict__ l_hs,
                                              int* __restrict__ offs,
                                              int* __restrict__ seg,
                                              int Bn, int Tn, int Mp) {
  const int tid = threadIdx.x;
  if (blockIdx.x == 0) {
    __shared__ int so[65];
    if (tid < 64) {
      int v = (tid < Bn) ? l_hs[tid] : 0;
#pragma unroll
      for (int off = 1; off < 64; off <<= 1) {
        int up = __shfl_up(v, off, 64);
        if (tid >= off) v += up;
      }
      so[tid + 1] = v;
      if (tid == 0) so[0] = 0;
    }
    __syncthreads();
    if (tid < 65) offs[tid] = so[tid];
    for (int t = tid; t < Mp; t += 256) {
      int s = 0;
      if (t < Tn) {
        int lo = 0, hi = Bn;
        while (hi - lo > 1) {
          int mid = (lo + hi) >> 1;
          if (so[mid] <= t) lo = mid; else hi = mid;
        }
        s = lo;
      }
      seg[t] = s;
    }
  }
  const int i = blockIdx.x * 1024 + tid * 4;  // [0, 1M)
  const int r = i >> 10, k = i & 1023;
  float4 v = *(const float4*)&enc_w[(size_t)r * 2048 + k];
  uint2 pk;
  pk.x = (u32)f2bf(v.x) | ((u32)f2bf(v.y) << 16);
  pk.y = (u32)f2bf(v.z) | ((u32)f2bf(v.w) << 16);
  *(uint2*)&W1[i] = pk;
}

// ---- k_ctxmm: out[b,d] = bias[d] + ctx[b,:]·W[d, colOff:colOff+1024]  ----
// grid (16 d-chunks of 64, 8 b-chunks of 8, 2); z=0 -> wencu(U), z=1 -> h2(enc right half)
__global__ __launch_bounds__(256) void k_ctxmm(const float* __restrict__ ctx,
                                               const float* __restrict__ U_w,
                                               const float* __restrict__ U_b,
                                               const float* __restrict__ enc_w,
                                               const float* __restrict__ enc_b,
                                               float* __restrict__ wencu,
                                               float* __restrict__ h2) {
  const int z = blockIdx.z;
  const float* W = z ? enc_w : U_w;
  const float* bias = z ? enc_b : U_b;
  float* outp = z ? h2 : wencu;
  const int ldW = z ? 2048 : 1024;
  const int colOff = z ? 1024 : 0;
  const int d0 = blockIdx.x * 64;
  const int b0 = blockIdx.y * 8;
  const int tid = threadIdx.x;
  const int dl = tid & 63;
  const int ks = tid >> 6;          // wave-uniform K-slice
  __shared__ float xs[8][IS_];      // 32 KB
  __shared__ float rs[4][64][8];    // 8 KB
#pragma unroll
  for (int it = 0; it < 8; ++it) {
    int i = it * 256 + tid;         // float4 index, 2048 total
    int bb = i >> 8, kk = (i & 255) * 4;
    *(float4*)&xs[bb][kk] = *(const float4*)&ctx[(size_t)(b0 + bb) * IS_ + kk];
  }
  __syncthreads();
  const float* wr = W + (size_t)(d0 + dl) * ldW + colOff + ks * 256;
  float acc[8] = {0, 0, 0, 0, 0, 0, 0, 0};
#pragma unroll 4
  for (int k = 0; k < 256; k += 4) {
    float4 w4 = *(const float4*)(wr + k);
#pragma unroll
    for (int b = 0; b < 8; ++b) {
      float4 x4 = *(const float4*)&xs[b][ks * 256 + k];
      acc[b] += dot4(w4, x4);
    }
  }
#pragma unroll
  for (int b = 0; b < 8; ++b) rs[ks][dl][b] = acc[b];
  __syncthreads();
#pragma unroll
  for (int rep = 0; rep < 2; ++rep) {
    int o = rep * 256 + tid;        // 512 outputs: d=o>>3, b=o&7
    int dd = o >> 3, bb = o & 7;
    float v = bias[d0 + dd] + rs[0][dd][bb] + rs[1][dd][bb] + rs[2][dd][bb] + rs[3][dd][bb];
    outp[(size_t)(b0 + bb) * IS_ + d0 + dd] = v;
  }
}

// ---- k_q2: q2[b,e] = sum_d wencu[b,d] * V_w[d,e] ----
// grid (16 e-chunks of 64, 16 b-chunks of 4)
__global__ __launch_bounds__(256) void k_q2(const float* __restrict__ wencu,
                                            const float* __restrict__ Vw,
                                            float* __restrict__ q2) {
  const int e0 = blockIdx.x * 64;
  const int b0 = blockIdx.y * 4;
  const int tid = threadIdx.x;
  const int el = tid & 63;
  const int ks = tid >> 6;          // wave-uniform d-slice
  __shared__ float xs[4][IS_];      // 16 KB
  __shared__ float rs[4][64][4];    // 4 KB
#pragma unroll
  for (int it = 0; it < 4; ++it) {
    int i = it * 256 + tid;         // float4 index, 1024 total
    int bb = i >> 8, kk = (i & 255) * 4;
    *(float4*)&xs[bb][kk] = *(const float4*)&wencu[(size_t)(b0 + bb) * IS_ + kk];
  }
  __syncthreads();
  const int dbase = ks * 256;
  float acc[4] = {0, 0, 0, 0};
#pragma unroll 4
  for (int d = 0; d < 256; ++d) {
    float v = Vw[(size_t)(dbase + d) * IS_ + e0 + el];
#pragma unroll
    for (int b = 0; b < 4; ++b) acc[b] += xs[b][dbase + d] * v;
  }
#pragma unroll
  for (int b = 0; b < 4; ++b) rs[ks][el][b] = acc[b];
  __syncthreads();
  int o = tid;                      // 256 outputs: e=o>>2, b=o&3
  int ee = o >> 2, bb = o & 3;
  float v = rs[0][ee][bb] + rs[1][ee][bb] + rs[2][ee][bb] + rs[3][ee][bb];
  q2[(size_t)(b0 + bb) * IS_ + e0 + ee] = v;
}

// ---------------- k_attn: scores + softmax + pooled (bf16) ----------------
__global__ __launch_bounds__(256) void k_attn(const float* __restrict__ wemb,
                                              const float* __restrict__ q2,
                                              const int* __restrict__ seg,
                                              u16* __restrict__ pooled, int Tn) {
  const int t = blockIdx.x;
  const int tid = threadIdx.x;
  const int d4 = tid * 4;
  if (t >= Tn) {
    uint2 z; z.x = 0u; z.y = 0u;
    *(uint2*)&pooled[(size_t)t * IS_ + d4] = z;
    return;
  }
  const int b = seg[t];
  float4 q = *(const float4*)&q2[b * IS_ + d4];
  float4 w[LTOK];
  const float* base = wemb + (size_t)t * (LTOK * IS_) + d4;
#pragma unroll
  for (int l = 0; l < LTOK; ++l) w[l] = *(const float4*)(base + l * IS_);
  float s[LTOK];
#pragma unroll
  for (int l = 0; l < LTOK; ++l) s[l] = dot4(w[l], q);
  const int wave = tid >> 6, lane = tid & 63;
  // reduce-scatter butterfly: 15 shuffles to 1 value/lane (idx = bitrev4(lane&15))
#pragma unroll
  for (int m = 1; m <= 8; m <<= 1) {
    const int live = 16 / m;        // 16,8,4,2
    const int half = live >> 1;
    const bool hi = (lane & m) != 0;
#pragma unroll
    for (int i = 0; i < half; ++i) {
      float tosend = hi ? s[i] : s[i + half];
      float recv = __shfl_xor(tosend, m, 64);
      float keep = hi ? s[i + half] : s[i];
      s[i] = keep + recv;
    }
  }
  s[0] += __shfl_xor(s[0], 16, 64);
  s[0] += __shfl_xor(s[0], 32, 64);
  __shared__ float sred[4][LTOK];
  if (lane < 16) {
    int v = ((lane & 1) << 3) | ((lane & 2) << 1) | ((lane & 4) >> 1) | ((lane & 8) >> 3);
    sred[wave][v] = s[0];
  }
  __syncthreads();
  float sc[LTOK];
#pragma unroll
  for (int l = 0; l < LTOK; ++l)
    sc[l] = sred[0][l] + sred[1][l] + sred[2][l] + sred[3][l];
  float mx = sc[0];
#pragma unroll
  for (int l = 1; l < LTOK; ++l) mx = fmaxf(mx, sc[l]);
  float den = 0.f;
#pragma unroll
  for (int l = 0; l < LTOK; ++l) { sc[l] = __expf(sc[l] - mx); den += sc[l]; }
  const float inv = 1.f / den;
  float px = 0.f, py = 0.f, pz = 0.f, pw = 0.f;
#pragma unroll
  for (int l = 0; l < LTOK; ++l) {
    float a = sc[l] * inv;
    px += a * w[l].x; py += a * w[l].y; pz += a * w[l].z; pw += a * w[l].w;
  }
  uint2 pk;
  pk.x = (u32)f2bf(px) | ((u32)f2bf(py) << 16);
  pk.y = (u32)f2bf(pz) | ((u32)f2bf(pw) << 16);
  *(uint2*)&pooled[(size_t)t * IS_ + d4] = pk;
}

// ---------------- k_gemm: h[M,1024] = pooled[M,1024] @ W1[1024,1024]^T -----
__device__ __forceinline__ void gl2lds16(const void* g, void* l) {
  __builtin_amdgcn_global_load_lds(
      (const __attribute__((address_space(1))) u32*)g,
      (__attribute__((address_space(3))) u32*)l, 16, 0, 0);
}

__global__ __launch_bounds__(256) void k_gemm(const u16* __restrict__ A,
                                              const u16* __restrict__ B,
                                              float* __restrict__ C) {
  __shared__ __align__(16) u16 As[128 * 64];
  __shared__ __align__(16) u16 Bs[128 * 64];
  const int tid = threadIdx.x;
  const int wave = tid >> 6, lane = tid & 63;
  const int m0 = blockIdx.x * 128, n0 = blockIdx.y * 128;
  const int wm = (wave & 1) * 64, wn = (wave >> 1) * 64;
  f32x4 acc[4][4] = {};
  for (int kt = 0; kt < 1024; kt += 64) {
#pragma unroll
    for (int c = 0; c < 4; ++c) {
      int idx = c * 256 + tid;       // 0..1023
      int row = idx >> 3;            // 0..127
      int kk = (idx & 7) * 8;        // 0..56
      gl2lds16(A + (size_t)(m0 + row) * 1024 + kt + kk, &As[idx * 8]);
      gl2lds16(B + (size_t)(n0 + row) * 1024 + kt + kk, &Bs[idx * 8]);
    }
    __syncthreads();
#pragma unroll
    for (int ks = 0; ks < 2; ++ks) {
      const int kb = ks * 32 + (lane >> 4) * 8;
      const int rr = lane & 15;
      s16x8 af[4], bf[4];
#pragma unroll
      for (int i = 0; i < 4; ++i) {
        af[i] = *(const s16x8*)&As[(wm + i * 16 + rr) * 64 + kb];
        bf[i] = *(const s16x8*)&Bs[(wn + i * 16 + rr) * 64 + kb];
      }
#pragma unroll
      for (int i = 0; i < 4; ++i)
#pragma unroll
        for (int j = 0; j < 4; ++j)
          acc[i][j] = __builtin_amdgcn_mfma_f32_16x16x32_bf16(af[i], bf[j], acc[i][j], 0, 0, 0);
    }
    __syncthreads();
  }
  const int col = lane & 15, rq = (lane >> 4) * 4;
#pragma unroll
  for (int i = 0; i < 4; ++i)
#pragma unroll
    for (int j = 0; j < 4; ++j) {
#pragma unroll
      for (int r = 0; r < 4; ++r)
        C[(size_t)(m0 + wm + i * 16 + rq + r) * 1024 + (n0 + wn + j * 16 + col)] = acc[i][j][r];
    }
}

// ---------------- k_ln: +h2[seg], LayerNorm, scatter to padded -------------
__global__ __launch_bounds__(256) void k_ln(const float* __restrict__ h,
                                            const float* __restrict__ h2,
                                            const int* __restrict__ offs,
                                            const int* __restrict__ l_hs,
                                            const float* __restrict__ gamma,
                                            const float* __restrict__ beta,
                                            float* __restrict__ out, int maxL) {
  const int row = blockIdx.x;
  const int b = row / maxL, pos = row % maxL;
  const int tid = threadIdx.x, d4 = tid * 4;
  float4 be = *(const float4*)&beta[d4];
  float* orow = out + (size_t)row * IS_;
  if (pos >= l_hs[b]) {
    *(float4*)(orow + d4) = be;
    return;
  }
  const int t = offs[b] + pos;
  float4 x = *(const float4*)&h[(size_t)t * IS_ + d4];
  float4 y2 = *(const float4*)&h2[b * IS_ + d4];
  x.x += y2.x; x.y += y2.y; x.z += y2.z; x.w += y2.w;
  float s1 = x.x + x.y + x.z + x.w;
  float s2 = x.x * x.x + x.y * x.y + x.z * x.z + x.w * x.w;
#pragma unroll
  for (int m = 1; m < 64; m <<= 1) {
    s1 += __shfl_xor(s1, m, 64);
    s2 += __shfl_xor(s2, m, 64);
  }
  __shared__ float red[4][2];
  const int wave = tid >> 6, lane = tid & 63;
  if (lane == 0) { red[wave][0] = s1; red[wave][1] = s2; }
  __syncthreads();
  float S1 = red[0][0] + red[1][0] + red[2][0] + red[3][0];
  float S2 = red[0][1] + red[1][1] + red[2][1] + red[3][1];
  const float u = S1 * (1.f / 1024.f);
  const float var = S2 * (1.f / 1024.f) - u * u;
  const float rstd = rsqrtf(var + 1e-12f);
  float4 g = *(const float4*)&gamma[d4];
  float4 o;
  o.x = g.x * (x.x - u) * rstd + be.x;
  o.y = g.y * (x.y - u) * rstd + be.y;
  o.z = g.z * (x.z - u) * rstd + be.z;
  o.w = g.w * (x.w - u) * rstd + be.w;
  *(float4*)(orow + d4) = o;
}

extern "C" void kernel_launch(void* const* d_in, const int* in_sizes, int n_in,
                              void* d_out, int out_size, void* d_ws, size_t ws_size,
                              hipStream_t stream) {
  const float* ctx   = (const float*)d_in[0];
  const float* wemb  = (const float*)d_in[1];
  const int*   l_hs  = (const int*)d_in[3];
  const float* U_w   = (const float*)d_in[5];
  const float* U_b   = (const float*)d_in[6];
  const float* V_w   = (const float*)d_in[7];
  // d_in[8] = V_b: constant-per-row score shift -> cancels in softmax
  const float* enc_w = (const float*)d_in[9];
  const float* enc_b = (const float*)d_in[10];
  const float* gamma = (const float*)d_in[11];
  const float* beta  = (const float*)d_in[12];
  float* out = (float*)d_out;

  const int Bn = in_sizes[0] / IS_;               // 64
  const int Tn = in_sizes[1] / (LTOK * IS_);      // 4064
  const int maxL = out_size / (Bn * IS_);         // 95
  const int Mp = (Tn + 127) & ~127;               // 4096

  char* ws = (char*)d_ws;
  int*   offs   = (int*)(ws + 0x0);
  int*   seg    = (int*)(ws + 0x400);
  float* wencu  = (float*)(ws + 0x10000);
  float* q2     = (float*)(ws + 0x50000);
  float* h2     = (float*)(ws + 0x90000);
  u16*   W1     = (u16*)(ws + 0xD0000);
  u16*   pooled = (u16*)(ws + 0x2D0000);
  float* h      = (float*)(ws + 0xAD0000);

  k_prep<<<1024, 256, 0, stream>>>(enc_w, W1, l_hs, offs, seg, Bn, Tn, Mp);
  k_ctxmm<<<dim3(16, Bn / 8, 2), 256, 0, stream>>>(ctx, U_w, U_b, enc_w, enc_b, wencu, h2);
  k_q2<<<dim3(16, Bn / 4), 256, 0, stream>>>(wencu, V_w, q2);
  k_attn<<<Mp, 256, 0, stream>>>(wemb, q2, seg, pooled, Tn);
  k_gemm<<<dim3(Mp / 128, 8), 256, 0, stream>>>(pooled, W1, h);
  k_ln<<<Bn * maxL, 256, 0, stream>>>(h, h2, offs, l_hs, gamma, beta, out, maxL);
}